// Round 1
// baseline (58948.096 us; speedup 1.0000x reference)
//
#include <hip/hip_runtime.h>
#include <cstddef>

#define DEV __device__ __forceinline__

// ---- problem dims ----
// B=16 S=256 IN_DIM=264 KX=520 H=512 4H=2048 XI=471(pad 480) N=256 M=64 R=4 OUT=256

constexpr int S_ = 256;

// workspace layout (float offsets)
constexpr size_t OFF_H   = 0;         // h           16x512
constexpr size_t OFF_C   = 8192;      // c ping-pong 2x16x512
constexpr size_t OFF_MEM = 24576;     // mem         16x256x64
constexpr size_t OFF_NRM = 286720;    // ||mem_n||^2 16x256
constexpr size_t OFF_USG = 290816;    // usage       16x256
constexpr size_t OFF_LNK = 294912;    // link        16x256x256
constexpr size_t OFF_PRC = 1343488;   // prec ping-pong 2x16x256
constexpr size_t OFF_WR  = 1351680;   // w_r         16x4x256
constexpr size_t OFF_WW  = 1368064;   // w_w         16x256
constexpr size_t OFF_RV  = 1372160;   // r_vec       16x256
constexpr size_t ZERO_END= 1376256;   // state above zeroed at start
constexpr size_t OFF_GP  = 1376256;   // gates partials 4x16x2048
constexpr size_t OFF_XI  = 1507328;   // xi          16x480
constexpr size_t OFF_KNR = 1515008;   // normalized read keys * beta 16x256
constexpr size_t OFF_PI  = 1519104;   // pi          16x12 (pad 16)
constexpr size_t OFF_ERS = 1519360;   // erase       16x64
constexpr size_t OFF_WVC = 1520384;   // write vec   16x64
constexpr size_t OFF_FWD = 1521408;   // fwd         16x4x256
constexpr size_t OFF_BWD = 1537792;   // bwd         16x4x256
constexpr size_t OFF_ALC = 1554176;   // alloc       16x256
constexpr size_t OFF_CW  = 1558272;   // c_w         16x256
constexpr size_t OFF_SCL = 1562368;   // scalars g_a,g_w,sumAlloc per batch 16x4
constexpr size_t WS_TOTAL= 1562432;   // ~6.25 MB

DEV float sigm(float x){ return 1.0f/(1.0f+expf(-x)); }
DEV float oneplus_(float x){ float sp = (x>20.0f)? x : log1pf(expf(x)); return 1.0f+sp; }

DEV float wredsum(float v){
  #pragma unroll
  for (int o=32;o>0;o>>=1) v += __shfl_xor(v,o);
  return v;
}
DEV float wredmax(float v){
  #pragma unroll
  for (int o=32;o>0;o>>=1) v = fmaxf(v,__shfl_xor(v,o));
  return v;
}
// 256-thread block reductions (all threads must call)
DEV float bredsum(float v, float* red){
  v = wredsum(v);
  if ((threadIdx.x&63)==0) red[threadIdx.x>>6]=v;
  __syncthreads();
  float r = red[0]+red[1]+red[2]+red[3];
  __syncthreads();
  return r;
}
DEV float bredmax(float v, float* red){
  v = wredmax(v);
  if ((threadIdx.x&63)==0) red[threadIdx.x>>6]=v;
  __syncthreads();
  float r = fmaxf(fmaxf(red[0],red[1]),fmaxf(red[2],red[3]));
  __syncthreads();
  return r;
}

// ---------------- K0: zero persistent state ----------------
__global__ void k_zero(float* __restrict__ ws){
  size_t i = (size_t)blockIdx.x*blockDim.x + threadIdx.x;
  size_t st = (size_t)gridDim.x*blockDim.x;
  for (; i<ZERO_END; i+=st) ws[i]=0.0f;
}

// ---------------- K1: gates partial GEMMs (+ y output for t-1) ----------------
// blocks 0..255: gates. jc=blk>>2 (8 cols of 512), ks=blk&3 (k-quarter).
//   k quarters: ks0 Wx[0,260) ks1 Wx[260,520) ks2 Wh[0,256) ks3 Wh[256,512)
// blocks 256..287: y for step t-1 (skip at t==0). gates skip at t==S.
// 128 threads: b = tid&15, jj = tid>>4.
__global__ __launch_bounds__(128) void k_gates(
    const float* __restrict__ xin, const float* __restrict__ Wx,
    const float* __restrict__ Wh,  const float* __restrict__ blstm,
    const float* __restrict__ Wy,  const float* __restrict__ Wr,
    const float* __restrict__ by,  float* __restrict__ ws,
    float* __restrict__ out, int t)
{
  __shared__ float sh[13056]; // [k*17 + b] staging, padded stride kills bank conflicts
  const int tid = threadIdx.x;
  const int b = tid & 15, jj = tid >> 4;
  const float* h  = ws + OFF_H;
  const float* rv = ws + OFF_RV;

  if (blockIdx.x < 256) {
    if (t == S_) return;
    int jc = blockIdx.x >> 2;
    int ks = blockIdx.x & 3;
    int k0, kn; const float* W;
    if      (ks==0){ k0=0;   kn=260; W=Wx; }
    else if (ks==1){ k0=260; kn=260; W=Wx; }
    else if (ks==2){ k0=0;   kn=256; W=Wh; }
    else           { k0=256; kn=256; W=Wh; }
    for (int e=tid; e<kn*16; e+=128){
      int bb = e/kn, kk = e - bb*kn;
      int k = k0 + kk;
      float v;
      if (ks < 2) v = (k < 264) ? xin[((size_t)(bb*256 + t))*264 + k]
                                : rv[bb*256 + (k-264)];
      else        v = h[bb*512 + k];
      sh[kk*17 + bb] = v;
    }
    __syncthreads();
    int col = (jc<<3) + jj;
    float a0,a1,a2,a3;
    if (ks==0){ a0=blstm[col]; a1=blstm[512+col]; a2=blstm[1024+col]; a3=blstm[1536+col]; }
    else      { a0=0.f; a1=0.f; a2=0.f; a3=0.f; }
    const float* Wp = W + (size_t)k0*2048;
    #pragma unroll 4
    for (int kk=0; kk<kn; ++kk){
      float xv = sh[kk*17 + b];
      const float* wr = Wp + (size_t)kk*2048;
      a0 = fmaf(wr[col],      xv, a0);
      a1 = fmaf(wr[512+col],  xv, a1);
      a2 = fmaf(wr[1024+col], xv, a2);
      a3 = fmaf(wr[1536+col], xv, a3);
    }
    float* gp = ws + OFF_GP + (size_t)ks*32768 + (size_t)b*2048;
    gp[col] = a0; gp[512+col] = a1; gp[1024+col] = a2; gp[1536+col] = a3;
  } else {
    if (t == 0) return;
    int yb = blockIdx.x - 256;           // 0..31, 8 cols each
    for (int e=tid; e<768*16; e+=128){
      int bb = e/768, kk = e - bb*768;
      sh[kk*17+bb] = (kk<512) ? h[bb*512+kk] : rv[bb*256+(kk-512)];
    }
    __syncthreads();
    int col = (yb<<3) + jj;
    float acc = by[col];
    #pragma unroll 4
    for (int k=0;k<512;++k) acc = fmaf(sh[k*17+b], Wy[(size_t)k*256+col], acc);
    #pragma unroll 4
    for (int k=0;k<256;++k) acc = fmaf(sh[(512+k)*17+b], Wr[(size_t)k*256+col], acc);
    out[((size_t)(b*256 + (t-1)))*256 + col] = acc;
  }
}

// ---------------- K2: LSTM cell (redundant per block) + xi GEMM ----------------
// 15 blocks x 512 threads; block covers 32 xi columns for all 16 batches.
__global__ __launch_bounds__(512) void k_lstm_xi(
    const float* __restrict__ Wxi, const float* __restrict__ bxi,
    float* __restrict__ ws, int t)
{
  __shared__ float hl[512*17];
  const int tid = threadIdx.x;
  const float* gp0 = ws + OFF_GP;
  const float* gp1 = gp0 + 32768;
  const float* gp2 = gp0 + 65536;
  const float* gp3 = gp0 + 98304;
  const float* cold = ws + OFF_C + (size_t)(t&1)*8192;
  float* cnew = ws + OFF_C + (size_t)((t+1)&1)*8192;
  float* hg = ws + OFF_H;
  for (int e=tid; e<8192; e+=512){
    int bb = e>>9, j = e&511;
    size_t base = (size_t)bb*2048 + j;
    float gi = gp0[base]      + gp1[base]      + gp2[base]      + gp3[base];
    float gf = gp0[base+512]  + gp1[base+512]  + gp2[base+512]  + gp3[base+512];
    float gg = gp0[base+1024] + gp1[base+1024] + gp2[base+1024] + gp3[base+1024];
    float go = gp0[base+1536] + gp1[base+1536] + gp2[base+1536] + gp3[base+1536];
    float co = cold[bb*512+j];
    float cn = sigm(gf)*co + sigm(gi)*tanhf(gg);
    float hn = sigm(go)*tanhf(cn);
    hl[j*17+bb] = hn;
    if (blockIdx.x==0){ cnew[bb*512+j]=cn; hg[bb*512+j]=hn; }
  }
  __syncthreads();
  int b = tid&15, jj = tid>>4;
  int col = blockIdx.x*32 + jj;
  if (col < 471){
    float acc = bxi[col];
    #pragma unroll 4
    for (int k=0;k<512;++k) acc = fmaf(hl[k*17+b], Wxi[(size_t)k*471+col], acc);
    ws[OFF_XI + (size_t)b*480 + col] = acc;
  }
}

// ---------------- K3: per-batch control ----------------
// blocks 0..15  : psi/usage, stable rank-sort, cumprod scan, alloc, scalars,
//                 knr (read keys), pi, erase/wvec, zero bwd.   (batch = blk)
// blocks 16..31 : write-key content softmax -> cw.             (batch = blk-16)
__global__ __launch_bounds__(256) void k_ctrl(float* __restrict__ ws, int t)
{
  __shared__ float xv[480];
  __shared__ float uu[256], sa[256], sb[256];
  __shared__ float red[4];
  __shared__ float knw[64];
  __shared__ float sims[256];
  const int tid = threadIdx.x;
  const int bid = blockIdx.x;

  if (bid < 16){
    int b = bid;
    const float* xib = ws + OFF_XI + (size_t)b*480;
    for (int e=tid; e<480; e+=256) xv[e] = xib[e];
    __syncthreads();
    int n = tid;
    float f0=sigm(xv[453]), f1=sigm(xv[454]), f2=sigm(xv[455]), f3=sigm(xv[456]);
    const float* wrb = ws + OFF_WR + (size_t)b*1024;
    float psi = (1.f - f0*wrb[n]) * (1.f - f1*wrb[256+n])
              * (1.f - f2*wrb[512+n]) * (1.f - f3*wrb[768+n]);
    float uo  = ws[OFF_USG + b*256 + n];
    float wwp = ws[OFF_WW  + b*256 + n];
    float un = (uo + wwp - uo*wwp) * psi;
    uu[n] = un;
    ws[OFF_USG + b*256 + n] = un;
    __syncthreads();
    // stable ascending rank (== stable argsort w/ index tiebreak)
    int rk = 0;
    for (int j=0;j<256;++j){
      float uj = uu[j];
      rk += (uj < un) || (uj == un && j < n);
    }
    sa[rk] = un;
    __syncthreads();
    // inclusive cumprod scan (Hillis-Steele, 8 rounds)
    float* cur = sa; float* nxt = sb;
    for (int off=1; off<256; off<<=1){
      float v = cur[n];
      if (n >= off) v *= cur[n-off];
      nxt[n] = v;
      __syncthreads();
      float* tmp = cur; cur = nxt; nxt = tmp;
    }
    float pe = (rk==0) ? 1.f : cur[rk-1];
    float al = (1.f - un) * pe;
    ws[OFF_ALC + b*256 + n] = al;
    float sumA = bredsum(al, red);
    if (tid==0){
      ws[OFF_SCL + b*4 + 0] = sigm(xv[457]);   // g_a
      ws[OFF_SCL + b*4 + 1] = sigm(xv[458]);   // g_w
      ws[OFF_SCL + b*4 + 2] = sumA;
    }
    { // normalized read keys * beta_r
      int r = tid>>6, m = tid&63;
      float kv = xv[r*64+m];
      float s2 = wredsum(kv*kv);
      float br = oneplus_(xv[256+r]);
      ws[OFF_KNR + b*256 + tid] = kv * br / (sqrtf(s2) + 1e-6f);
    }
    if (tid < 4){ // pi softmax (3-way)
      float p0 = xv[459+tid*3], p1 = xv[460+tid*3], p2 = xv[461+tid*3];
      float mx = fmaxf(p0,fmaxf(p1,p2));
      float e0=expf(p0-mx), e1=expf(p1-mx), e2=expf(p2-mx);
      float s = e0+e1+e2;
      float* pg = ws + OFF_PI + b*12 + tid*3;
      pg[0]=e0/s; pg[1]=e1/s; pg[2]=e2/s;
    }
    if (tid < 64){
      ws[OFF_ERS + b*64 + tid] = sigm(xv[325+tid]);
      ws[OFF_WVC + b*64 + tid] = xv[389+tid];
    }
    float* bw = ws + OFF_BWD + (size_t)b*1024;
    bw[tid]=0.f; bw[256+tid]=0.f; bw[512+tid]=0.f; bw[768+tid]=0.f;
  } else {
    int b = bid - 16;
    const float* xib = ws + OFF_XI + (size_t)b*480;
    int lane = tid&63, wv = tid>>6;
    if (wv == 0){
      float kv = xib[260+lane];
      float s2 = wredsum(kv*kv);
      float bw_ = oneplus_(xib[324]);
      knw[lane] = kv * bw_ / (sqrtf(s2)+1e-6f);
    }
    __syncthreads();
    const float* memb = ws + OFF_MEM + (size_t)b*16384;
    const float* nr   = ws + OFF_NRM + (size_t)b*256;
    for (int it=0; it<64; ++it){
      int n = (wv<<6) + it;
      float v = memb[(n<<6) + lane];
      float d = wredsum(v * knw[lane]);
      if (lane==0) sims[n] = d / (sqrtf(nr[n]) + 1e-6f);
    }
    __syncthreads();
    float s = sims[tid];
    float mx = bredmax(s, red);
    float e = expf(s - mx);
    float sm = bredsum(e, red);
    ws[OFF_CW + b*256 + tid] = e / sm;
  }
}

// ---------------- K4: link update + fused fwd/bwd, mem update + norms + prec ----------------
// blocks 0..255: link rows. b=blk>>4, ic=blk&15 (16 rows), thread j=tid.
// blocks 256..319: mem update. b=(blk-256)>>2, nc=(blk-256)&3 (64 rows), wave per row.
__global__ __launch_bounds__(256) void k_memlink(float* __restrict__ ws, int t)
{
  __shared__ float wwi[16];
  __shared__ float wrl[4][16];
  __shared__ float fpart[4][4][16];
  const int tid = threadIdx.x;
  const int bid = blockIdx.x;

  if (bid < 256){
    int b = bid >> 4, ic = bid & 15;
    float ga = ws[OFF_SCL + b*4+0], gw = ws[OFF_SCL + b*4+1];
    int j = tid;
    float wj = gw*(ga*ws[OFF_ALC+b*256+j] + (1.f-ga)*ws[OFF_CW+b*256+j]);
    float pj = ws[OFF_PRC + (size_t)(t&1)*4096 + b*256 + j];
    float wr0 = ws[OFF_WR + (size_t)b*1024 + j];
    float wr1 = ws[OFF_WR + (size_t)b*1024 + 256 + j];
    float wr2 = ws[OFF_WR + (size_t)b*1024 + 512 + j];
    float wr3 = ws[OFF_WR + (size_t)b*1024 + 768 + j];
    if (tid < 16){
      int i = ic*16+tid;
      wwi[tid] = gw*(ga*ws[OFF_ALC+b*256+i] + (1.f-ga)*ws[OFF_CW+b*256+i]);
    }
    if (tid < 64){
      wrl[tid>>4][tid&15] = ws[OFF_WR + (size_t)b*1024 + (size_t)(tid>>4)*256 + ic*16 + (tid&15)];
    }
    __syncthreads();
    float b0=0.f,b1=0.f,b2=0.f,b3=0.f;
    float* lrow = ws + OFF_LNK + (size_t)b*65536 + (size_t)ic*16*256;
    int lane = tid&63, wv = tid>>6;
    for (int il=0; il<16; ++il){
      int i = ic*16+il;
      float Lo = lrow[il*256 + j];
      float wi = wwi[il];
      float Ln = (1.f - wi - wj)*Lo + wi*pj;
      if (i == j) Ln = 0.f;
      lrow[il*256 + j] = Ln;
      float s0 = wredsum(Ln*wr0);
      float s1 = wredsum(Ln*wr1);
      float s2 = wredsum(Ln*wr2);
      float s3 = wredsum(Ln*wr3);
      if (lane==0){ fpart[wv][0][il]=s0; fpart[wv][1][il]=s1; fpart[wv][2][il]=s2; fpart[wv][3][il]=s3; }
      b0 = fmaf(Ln, wrl[0][il], b0);
      b1 = fmaf(Ln, wrl[1][il], b1);
      b2 = fmaf(Ln, wrl[2][il], b2);
      b3 = fmaf(Ln, wrl[3][il], b3);
    }
    __syncthreads();
    if (tid < 64){
      int r = tid>>4, il = tid&15;
      float s = fpart[0][r][il]+fpart[1][r][il]+fpart[2][r][il]+fpart[3][r][il];
      ws[OFF_FWD + (size_t)b*1024 + (size_t)r*256 + ic*16 + il] = s;
    }
    float* bwd = ws + OFF_BWD + (size_t)b*1024;
    atomicAdd(&bwd[j],     b0);
    atomicAdd(&bwd[256+j], b1);
    atomicAdd(&bwd[512+j], b2);
    atomicAdd(&bwd[768+j], b3);
  } else {
    int idx = bid - 256;
    int b = idx >> 2, nc = idx & 3;
    float ga = ws[OFF_SCL+b*4+0], gw = ws[OFF_SCL+b*4+1], sA = ws[OFF_SCL+b*4+2];
    float sww = gw*(ga*sA + (1.f-ga));   // sum(w_w) (softmax sums to 1)
    int lane = tid&63, wv = tid>>6;
    float er  = ws[OFF_ERS + b*64 + lane];
    float wvv = ws[OFF_WVC + b*64 + lane];
    float* memb = ws + OFF_MEM + (size_t)b*16384;
    for (int it=0; it<16; ++it){
      int n = nc*64 + wv*16 + it;
      float wwn = gw*(ga*ws[OFF_ALC+b*256+n] + (1.f-ga)*ws[OFF_CW+b*256+n]);
      float v = memb[(n<<6)+lane];
      v = v*(1.f - wwn*er) + wwn*wvv;
      memb[(n<<6)+lane] = v;
      float s2 = wredsum(v*v);
      if (lane==0){
        ws[OFF_NRM + b*256 + n] = s2;
        ws[OFF_WW  + b*256 + n] = wwn;
        float po = ws[OFF_PRC + (size_t)(t&1)*4096 + b*256 + n];
        ws[OFF_PRC + (size_t)((t+1)&1)*4096 + b*256 + n] = (1.f - sww)*po + wwn;
      }
    }
  }
}

// ---------------- K5: read content softmax + w_r + r_vec ----------------
// 64 blocks x 256: b=blk>>2, r=blk&3; wave per memory row.
__global__ __launch_bounds__(256) void k_read(float* __restrict__ ws, int t)
{
  __shared__ float knl[64];
  __shared__ float sims[256];
  __shared__ float wrs[256];
  __shared__ float part[4][64];
  __shared__ float red[4];
  const int tid=threadIdx.x, lane=tid&63, wv=tid>>6;
  const int b = blockIdx.x>>2, r = blockIdx.x&3;
  if (wv==0) knl[lane] = ws[OFF_KNR + b*256 + r*64 + lane];
  __syncthreads();
  const float* memb = ws + OFF_MEM + (size_t)b*16384;
  const float* nr   = ws + OFF_NRM + (size_t)b*256;
  for (int it=0; it<64; ++it){
    int n = (wv<<6)+it;
    float v = memb[(n<<6)+lane];
    float d = wredsum(v*knl[lane]);
    if (lane==0) sims[n] = d / (sqrtf(nr[n])+1e-6f);
  }
  __syncthreads();
  float s = sims[tid];
  float mx = bredmax(s, red);
  float e = expf(s-mx);
  float sm = bredsum(e, red);
  float cr = e/sm;
  float p0 = ws[OFF_PI + b*12 + r*3+0];
  float p1 = ws[OFF_PI + b*12 + r*3+1];
  float p2 = ws[OFF_PI + b*12 + r*3+2];
  float wr = p0*ws[OFF_BWD+(size_t)b*1024+r*256+tid] + p1*cr
           + p2*ws[OFF_FWD+(size_t)b*1024+r*256+tid];
  ws[OFF_WR + (size_t)b*1024 + r*256 + tid] = wr;
  wrs[tid] = wr;
  __syncthreads();
  float acc = 0.f;
  for (int it=0; it<64; ++it){
    int n = (wv<<6)+it;
    acc = fmaf(wrs[n], memb[(n<<6)+lane], acc);
  }
  part[wv][lane] = acc;
  __syncthreads();
  if (tid < 64){
    ws[OFF_RV + b*256 + r*64 + tid] = part[0][tid]+part[1][tid]+part[2][tid]+part[3][tid];
  }
}

extern "C" void kernel_launch(void* const* d_in, const int* in_sizes, int n_in,
                              void* d_out, int out_size, void* d_ws, size_t ws_size,
                              hipStream_t stream) {
  (void)in_sizes; (void)out_size;
  if (n_in < 9) return;
  const float* xin = (const float*)d_in[0];
  const float* Wx  = (const float*)d_in[1];
  const float* Wh  = (const float*)d_in[2];
  const float* bl  = (const float*)d_in[3];
  const float* Wxi = (const float*)d_in[4];
  const float* bxi = (const float*)d_in[5];
  const float* Wy  = (const float*)d_in[6];
  const float* Wr  = (const float*)d_in[7];
  const float* by  = (const float*)d_in[8];
  float* out = (float*)d_out;
  float* ws  = (float*)d_ws;
  if (ws_size < WS_TOTAL*sizeof(float)) return;

  hipLaunchKernelGGL(k_zero, dim3(1024), dim3(256), 0, stream, ws);
  for (int t=0; t<=S_; ++t){
    hipLaunchKernelGGL(k_gates, dim3(288), dim3(128), 0, stream,
                       xin, Wx, Wh, bl, Wy, Wr, by, ws, out, t);
    if (t < S_){
      hipLaunchKernelGGL(k_lstm_xi, dim3(15),  dim3(512), 0, stream, Wxi, bxi, ws, t);
      hipLaunchKernelGGL(k_ctrl,    dim3(32),  dim3(256), 0, stream, ws, t);
      hipLaunchKernelGGL(k_memlink, dim3(320), dim3(256), 0, stream, ws, t);
      hipLaunchKernelGGL(k_read,    dim3(64),  dim3(256), 0, stream, ws, t);
    }
  }
}